// Round 8
// baseline (6325.895 us; speedup 1.0000x reference)
//
#include <hip/hip_runtime.h>
#include <hip/hip_bf16.h>

typedef __attribute__((ext_vector_type(8))) short short8;
typedef __attribute__((ext_vector_type(4))) float floatx4;

#define IN_DIM  4096
#define OUT_DIM 4096
#define MROWS   16384
#define GSIZE   128

template <int N> struct IC { static constexpr int value = N; };

__device__ __forceinline__ unsigned short f2bf(float f) {
    unsigned int u = __builtin_bit_cast(unsigned int, f);
    u = (u + 0x7fffu + ((u >> 16) & 1u)) >> 16;
    return (unsigned short)u;
}

#define GLD16(gsrc, ldst)                                                     \
    __builtin_amdgcn_global_load_lds(                                         \
        (const __attribute__((address_space(1))) unsigned int*)(const void*)(gsrc), \
        (__attribute__((address_space(3))) unsigned int*)(void*)(ldst),       \
        16, 0, 0)

// ---------------------------------------------------------------- convert x
__global__ void convert_x(const float* __restrict__ x,
                          unsigned short* __restrict__ xb, int n8) {
    int stride = gridDim.x * blockDim.x;
    for (int i = blockIdx.x * blockDim.x + threadIdx.x; i < n8; i += stride) {
        const float4* xf = (const float4*)x;
        float4 f0 = xf[2 * i];
        float4 f1 = xf[2 * i + 1];
        union { unsigned short u[8]; uint4 v; } pk;
        pk.u[0] = f2bf(f0.x); pk.u[1] = f2bf(f0.y);
        pk.u[2] = f2bf(f0.z); pk.u[3] = f2bf(f0.w);
        pk.u[4] = f2bf(f1.x); pk.u[5] = f2bf(f1.y);
        pk.u[6] = f2bf(f1.z); pk.u[7] = f2bf(f1.w);
        ((uint4*)xb)[i] = pk.v;
    }
}

// ---------------------------------------------------------------- decode W
__global__ void decode_w(const int* __restrict__ pw,
                         const float* __restrict__ norms,
                         const float* __restrict__ s1,
                         const float* __restrict__ s2,
                         const float* __restrict__ cent,
                         unsigned short* __restrict__ W) {
    int row  = blockIdx.x * 4 + (threadIdx.x >> 6);
    int lane = threadIdx.x & 63;
    float nrm = norms[row];
    int c0 = pw[(size_t)row * GSIZE + lane];
    int c1 = pw[(size_t)row * GSIZE + lane + 64];
    float e0 = cent[c0] * nrm * s2[lane];
    float e1 = cent[c1] * nrm * s2[lane + 64];
#pragma unroll
    for (int it = 0; it < 7; ++it) {
        float a = e0, b = e1;
        e0 = a + b;
        e1 = a - b;
    }
    const float inv = 0.08838834764831845f; // 1/sqrt(128)
    int o = row >> 5, g = row & 31;
    unsigned short* wr = W + (size_t)o * IN_DIM + g * GSIZE;
    wr[lane]      = f2bf(e0 * inv * s1[lane]);
    wr[lane + 64] = f2bf(e1 * inv * s1[lane + 64]);
}

// ---------------------------------------------------------------- GEMM
// 256x256 tile, BK=64, 8 waves (2M x 4N). Minimal-control pipeline
// (same as R7) with the VGPR cap LIFTED: __launch_bounds__(512, 1).
// LDS (128 KiB) limits residency to 1 block/CU regardless, so the old
// (512,2) bound only capped VGPR at 128 and forced a ~100-reg spill
// (R7: 17 GB scratch writes). Live set acc(128) + frags(96) + addr fits
// in the 256-VGPR/wave budget at 8 waves/CU.
//
// Per K-tile j (BF = j&1), per wave:
//   MFMA ks0(j)            (operands read last tile; counted lgkm by compiler)
//   lgkmcnt(0)             (WAR cert: all my reads of BF complete)
//   barrier #1 + fence     (BF free block-wide)
//   STG(j+2 -> BF)         (8 global_load_lds)
//   vmcnt(8) cold          (tile j+1 loads, issued 1 tile ago, all landed)
//   barrier #2 + fence     (RAW globalized: tile j+1 readable)
//   issue ds_read ks0(j+1) (12 reads, drain under MFMA ks1)
//   MFMA ks1(j)
//   issue ds_read ks1(j+1) (12 reads, drain into next tile's MFMA ks0)
__global__ __launch_bounds__(512, 1)
void gemm_bf16(const unsigned short* __restrict__ Xg,
               const unsigned short* __restrict__ Wg,
               const float* __restrict__ bias,
               float* __restrict__ out) {
    __shared__ unsigned short As[2][256][64];
    __shared__ unsigned short Bs[2][256][64];

    // bijective XCD swizzle (1024 blocks % 8 == 0); consecutive ids share mt
    int id = (blockIdx.x & 7) * 128 + (blockIdx.x >> 3);
    int mt = id >> 4, nt = id & 15;
    int m0 = mt * 256, n0 = nt * 256;

    int tid  = threadIdx.x;
    int lane = tid & 63;
    int wid  = tid >> 6;
    int wm = wid >> 2, wn = wid & 3;   // wave tile: rows wm*128+, cols wn*64+

    // staging: thread handles 16B phys chunk cp0 of rows sr0 / sr0+64(+128)
    int sr0 = tid >> 3;        // 0..63
    int cp0 = tid & 7;         // physical chunk position
    int sg0 = cp0 ^ (sr0 & 7); // global chunk (inverse swizzle)

#define STG_AH(bufc, h, j) do {                                               \
    const unsigned short* _s =                                                \
        Xg + (size_t)(m0 + (h)*64 + sr0) * IN_DIM + (size_t)(j)*64 + sg0*8;   \
    GLD16(_s,                 &As[bufc][(h)*64 + sr0][cp0 * 8]);              \
    GLD16(_s + 128 * IN_DIM,  &As[bufc][128 + (h)*64 + sr0][cp0 * 8]);        \
  } while (0)
#define STG_BH(bufc, h, j) do {                                               \
    const unsigned short* _s =                                                \
        Wg + (size_t)(n0 + (h)*128 + sr0) * IN_DIM + (size_t)(j)*64 + sg0*8;  \
    GLD16(_s,                &Bs[bufc][(h)*128 + sr0][cp0 * 8]);              \
    GLD16(_s + 64 * IN_DIM,  &Bs[bufc][(h)*128 + sr0 + 64][cp0 * 8]);         \
  } while (0)
#define STG_TILE(bufc, j) do {                                                \
    STG_BH(bufc, 0, j); STG_BH(bufc, 1, j);                                   \
    STG_AH(bufc, 0, j); STG_AH(bufc, 1, j);                                   \
  } while (0)

    int rl = lane & 15, kc = lane >> 4;
    short8 a_[8][2], b_[4][2];
    floatx4 acc[8][4] = {};

#define LD_A(BFc, m, ks) do {                                                 \
    int row_ = wm * 128 + (m)*16 + rl;                                        \
    a_[m][ks] = *(const short8*)&As[BFc][row_][((((ks)*4 + kc) ^ (row_ & 7)) << 3)]; \
  } while (0)
#define LD_B(BFc, n, ks) do {                                                 \
    int row_ = wn * 64 + (n)*16 + rl;                                         \
    b_[n][ks] = *(const short8*)&Bs[BFc][row_][((((ks)*4 + kc) ^ (row_ & 7)) << 3)]; \
  } while (0)
#define LD_SLICE(BFc, ks) do {                                                \
    LD_B(BFc, 0, ks); LD_B(BFc, 1, ks); LD_B(BFc, 2, ks); LD_B(BFc, 3, ks);   \
    LD_A(BFc, 0, ks); LD_A(BFc, 1, ks); LD_A(BFc, 2, ks); LD_A(BFc, 3, ks);   \
    LD_A(BFc, 4, ks); LD_A(BFc, 5, ks); LD_A(BFc, 6, ks); LD_A(BFc, 7, ks);   \
  } while (0)

#define MFMA_KS(ks) do {                                                      \
    __builtin_amdgcn_s_setprio(1);                                            \
    _Pragma("unroll") for (int m = 0; m < 8; ++m) {                           \
      _Pragma("unroll") for (int n = 0; n < 4; ++n)                           \
        acc[m][n] = __builtin_amdgcn_mfma_f32_16x16x32_bf16(                  \
            a_[m][ks], b_[n][ks], acc[m][n], 0, 0, 0);                        \
    }                                                                         \
    __builtin_amdgcn_s_setprio(0);                                            \
  } while (0)

    // ---- prologue: stage tiles 0,1; certify tile0; prefetch both ks of 0
    STG_TILE(0, 0);
    STG_TILE(1, 1);
    asm volatile("s_waitcnt vmcnt(8)" ::: "memory");  // tile0 resident
    __builtin_amdgcn_s_barrier();
    asm volatile("" ::: "memory");
    LD_SLICE(0, 0);
    LD_SLICE(0, 1);

    // MODE: 2 = steady; 1 = j=62 (no STG, vmcnt(0), still prefetch j+1);
    //       0 = j=63 (tail: no sync, no prefetch)
    auto body = [&](int j, auto bfc, auto modec) {
        constexpr int BF   = decltype(bfc)::value;
        constexpr int MODE = decltype(modec)::value;
        MFMA_KS(0);                                   // counted lgkm by compiler
        if constexpr (MODE >= 1) {
            asm volatile("s_waitcnt lgkmcnt(0)" ::: "memory"); // my BF reads done
            __builtin_amdgcn_s_barrier();                       // #1: BF free
            asm volatile("" ::: "memory");
            if constexpr (MODE == 2) {
                STG_TILE(BF, j + 2);
                asm volatile("s_waitcnt vmcnt(8)" ::: "memory"); // j+1 landed
            } else {
                asm volatile("s_waitcnt vmcnt(0)" ::: "memory"); // j+1 landed
            }
            __builtin_amdgcn_s_barrier();                       // #2: j+1 readable
            asm volatile("" ::: "memory");
            LD_SLICE(BF ^ 1, 0);                                // ks0(j+1)
        }
        MFMA_KS(1);
        if constexpr (MODE >= 1) LD_SLICE(BF ^ 1, 1);           // ks1(j+1)
    };

    for (int j = 0; j < 62; j += 2) {
        body(j,     IC<0>{}, IC<2>{});
        body(j + 1, IC<1>{}, IC<2>{});
    }
    body(62, IC<0>{}, IC<1>{});
    body(63, IC<1>{}, IC<0>{});

    // ---- epilogue: C/D layout col = lane&15, row = (lane>>4)*4 + i
    int q = lane >> 4;
#pragma unroll
    for (int n = 0; n < 4; ++n) {
        int col = n0 + wn * 64 + n * 16 + rl;
        float bv = bias[col];
#pragma unroll
        for (int m = 0; m < 8; ++m) {
#pragma unroll
            for (int i = 0; i < 4; ++i) {
                int row = m0 + wm * 128 + m * 16 + q * 4 + i;
                out[(size_t)row * OUT_DIM + col] = acc[m][n][i] + bv;
            }
        }
    }
#undef STG_AH
#undef STG_BH
#undef STG_TILE
#undef LD_A
#undef LD_B
#undef LD_SLICE
#undef MFMA_KS
}

// ---------------------------------------------------------------- launch
extern "C" void kernel_launch(void* const* d_in, const int* in_sizes, int n_in,
                              void* d_out, int out_size, void* d_ws, size_t ws_size,
                              hipStream_t stream) {
    const float* x     = (const float*)d_in[0];
    const int*   pw    = (const int*)d_in[1];
    const float* norms = (const float*)d_in[2];
    const float* s1    = (const float*)d_in[3];
    const float* s2    = (const float*)d_in[4];
    const float* cent  = (const float*)d_in[5];
    const float* bias  = (const float*)d_in[6];
    float* out = (float*)d_out;

    size_t needX = (size_t)MROWS * IN_DIM * 2;    // 128 MB
    size_t needW = (size_t)OUT_DIM * IN_DIM * 2;  //  32 MB
    if (ws_size < needX + needW) return;

    unsigned short* Xb = (unsigned short*)d_ws;
    unsigned short* Wb = (unsigned short*)((char*)d_ws + needX);

    convert_x<<<2048, 256, 0, stream>>>(x, Xb, MROWS * IN_DIM / 8);
    decode_w<<<(OUT_DIM * 32) / 4, 256, 0, stream>>>(pw, norms, s1, s2, cent, Wb);
    gemm_bf16<<<(MROWS / 256) * (OUT_DIM / 256), 512, 0, stream>>>(Xb, Wb, bias, out);
}

// Round 9
// 722.276 us; speedup vs baseline: 8.7583x; 8.7583x over previous
//
#include <hip/hip_runtime.h>
#include <hip/hip_bf16.h>

typedef __attribute__((ext_vector_type(8))) short short8;
typedef __attribute__((ext_vector_type(4))) float floatx4;

#define IN_DIM  4096
#define OUT_DIM 4096
#define MROWS   16384
#define GSIZE   128

template <int N> struct IC { static constexpr int value = N; };

__device__ __forceinline__ unsigned short f2bf(float f) {
    unsigned int u = __builtin_bit_cast(unsigned int, f);
    u = (u + 0x7fffu + ((u >> 16) & 1u)) >> 16;
    return (unsigned short)u;
}

#define GLD16(gsrc, ldst)                                                     \
    __builtin_amdgcn_global_load_lds(                                         \
        (const __attribute__((address_space(1))) unsigned int*)(const void*)(gsrc), \
        (__attribute__((address_space(3))) unsigned int*)(void*)(ldst),       \
        16, 0, 0)

// ---------------------------------------------------------------- convert x
__global__ void convert_x(const float* __restrict__ x,
                          unsigned short* __restrict__ xb, int n8) {
    int stride = gridDim.x * blockDim.x;
    for (int i = blockIdx.x * blockDim.x + threadIdx.x; i < n8; i += stride) {
        const float4* xf = (const float4*)x;
        float4 f0 = xf[2 * i];
        float4 f1 = xf[2 * i + 1];
        union { unsigned short u[8]; uint4 v; } pk;
        pk.u[0] = f2bf(f0.x); pk.u[1] = f2bf(f0.y);
        pk.u[2] = f2bf(f0.z); pk.u[3] = f2bf(f0.w);
        pk.u[4] = f2bf(f1.x); pk.u[5] = f2bf(f1.y);
        pk.u[6] = f2bf(f1.z); pk.u[7] = f2bf(f1.w);
        ((uint4*)xb)[i] = pk.v;
    }
}

// ---------------------------------------------------------------- decode W
__global__ void decode_w(const int* __restrict__ pw,
                         const float* __restrict__ norms,
                         const float* __restrict__ s1,
                         const float* __restrict__ s2,
                         const float* __restrict__ cent,
                         unsigned short* __restrict__ W) {
    int row  = blockIdx.x * 4 + (threadIdx.x >> 6);
    int lane = threadIdx.x & 63;
    float nrm = norms[row];
    int c0 = pw[(size_t)row * GSIZE + lane];
    int c1 = pw[(size_t)row * GSIZE + lane + 64];
    float e0 = cent[c0] * nrm * s2[lane];
    float e1 = cent[c1] * nrm * s2[lane + 64];
#pragma unroll
    for (int it = 0; it < 7; ++it) {
        float a = e0, b = e1;
        e0 = a + b;
        e1 = a - b;
    }
    const float inv = 0.08838834764831845f; // 1/sqrt(128)
    int o = row >> 5, g = row & 31;
    unsigned short* wr = W + (size_t)o * IN_DIM + g * GSIZE;
    wr[lane]      = f2bf(e0 * inv * s1[lane]);
    wr[lane + 64] = f2bf(e1 * inv * s1[lane + 64]);
}

// ---------------------------------------------------------------- GEMM
// 256x256 tile, BK=64, 8 waves (2M x 4N). Quadrant-rotation pipeline with
// register-liveness engineered to fit the 256-reg/wave budget (2 waves/SIMD):
// frag groups a0,a1,b0,b1 are SINGLE-buffered variables, re-read one-phase-
// ahead only after their last consuming quadrant.
//
// Phases per K-tile j (BF=j&1, OF=BF^1):
//  p1: read a1<-A1(j)[8]; stage A1,B1(j+1)->OF; MFMA Q1(m0-3,n0-1); barrier
//  p2: read b1<-B1(j)[4]; MFMA Q2(m4-7,n0-1); vmcnt(4); barrier
//  p3: MFMA Q3(m0-3,n2-3); read a0<-A0(j+1)[8]; stage B0(j+2)->BF; barrier
//  p4: MFMA Q4(m4-7,n2-3); read b0<-B0(j+1)[4]; stage A0(j+2)->BF; vmcnt(4); barrier
//
// Hazard ledger:
//  WAR(LDS regions): A1/B1(OF) freed by p4(j-1) barrier (consumed Q2/Q4);
//    B0(BF) freed by p2 barrier (Q1,Q2); A0(BF) freed by p3 barrier (Q1,Q3).
//  RAW(staged tiles): vmcnt(4)@p2 certifies A0,B0(j+1) (issued p3/p4(j-1),
//    2-3 phases cold) before p3/p4 reads; vmcnt(4)@p4 certifies A1,B1(j+1)
//    (issued p1(j), 3 phases cold) before p1/p2(j+1) reads.
//  Operand RAW: compiler-inserted counted lgkmcnt (all reads >=1 phase ahead).
//  Register WAR: each frag group re-read only after its last quadrant.
__global__ __launch_bounds__(512)
__attribute__((amdgpu_waves_per_eu(2, 2)))
void gemm_bf16(const unsigned short* __restrict__ Xg,
               const unsigned short* __restrict__ Wg,
               const float* __restrict__ bias,
               float* __restrict__ out) {
    __shared__ unsigned short As[2][256][64];
    __shared__ unsigned short Bs[2][256][64];

    // bijective XCD swizzle (1024 blocks % 8 == 0); consecutive ids share mt
    int id = (blockIdx.x & 7) * 128 + (blockIdx.x >> 3);
    int mt = id >> 4, nt = id & 15;
    int m0 = mt * 256, n0 = nt * 256;

    int tid  = threadIdx.x;
    int lane = tid & 63;
    int wid  = tid >> 6;
    int wm = wid >> 2, wn = wid & 3;   // wave tile: rows wm*128+, cols wn*64+

    int sr0 = tid >> 3;        // 0..63
    int cp0 = tid & 7;         // physical 16B-chunk position
    int sg0 = cp0 ^ (sr0 & 7); // global chunk (inverse swizzle)

// A-region h: h=0 -> rows {0-63,128-191} (m-frags 0-3); h=1 -> +64 (m 4-7)
#define STG_AH(bufc, h, j) do {                                               \
    const unsigned short* _s =                                                \
        Xg + (size_t)(m0 + (h)*64 + sr0) * IN_DIM + (size_t)(j)*64 + sg0*8;   \
    GLD16(_s,                 &As[bufc][(h)*64 + sr0][cp0 * 8]);              \
    GLD16(_s + 128 * IN_DIM,  &As[bufc][128 + (h)*64 + sr0][cp0 * 8]);        \
  } while (0)
// B-region h: rows with (r>>5)&1 == h (cols n0-1 / n2-3 of every wave)
#define STG_BH2(bufc, h, j) do {                                              \
    int _br = (h)*32 + (sr0 & 31) + (sr0 >> 5) * 128;                         \
    const unsigned short* _s =                                                \
        Wg + (size_t)(n0 + _br) * IN_DIM + (size_t)(j)*64 + sg0*8;            \
    GLD16(_s,                &Bs[bufc][_br][cp0 * 8]);                        \
    GLD16(_s + 64 * IN_DIM,  &Bs[bufc][_br + 64][cp0 * 8]);                   \
  } while (0)

    int rl = lane & 15, kc = lane >> 4;
    short8 a0_[4][2], a1_[4][2], b0_[2][2], b1_[2][2];
    floatx4 acc[8][4] = {};

    // row&7 == rl&7 for every fragment row -> XOR term is row-independent
#define RD_A(BFc, mrow, ks)                                                   \
    (*(const short8*)&As[BFc][wm*128 + (mrow)*16 + rl][((((ks)*4 + kc) ^ (rl & 7)) << 3)])
#define RD_B(BFc, nrow, ks)                                                   \
    (*(const short8*)&Bs[BFc][wn*64 + (nrow)*16 + rl][((((ks)*4 + kc) ^ (rl & 7)) << 3)])

#define LD_A0(BFc) do { _Pragma("unroll") for (int m = 0; m < 4; ++m)         \
    { a0_[m][0] = RD_A(BFc, m, 0); a0_[m][1] = RD_A(BFc, m, 1); } } while (0)
#define LD_A1(BFc) do { _Pragma("unroll") for (int m = 0; m < 4; ++m)         \
    { a1_[m][0] = RD_A(BFc, m + 4, 0); a1_[m][1] = RD_A(BFc, m + 4, 1); } } while (0)
#define LD_B0(BFc) do { _Pragma("unroll") for (int n = 0; n < 2; ++n)         \
    { b0_[n][0] = RD_B(BFc, n, 0); b0_[n][1] = RD_B(BFc, n, 1); } } while (0)
#define LD_B1(BFc) do { _Pragma("unroll") for (int n = 0; n < 2; ++n)         \
    { b1_[n][0] = RD_B(BFc, n + 2, 0); b1_[n][1] = RD_B(BFc, n + 2, 1); } } while (0)

#define MFMA_Q(AF, BG, MO, NO) do {                                           \
    __builtin_amdgcn_s_setprio(1);                                            \
    _Pragma("unroll") for (int ks = 0; ks < 2; ++ks) {                        \
      _Pragma("unroll") for (int m = 0; m < 4; ++m) {                         \
        _Pragma("unroll") for (int n = 0; n < 2; ++n)                         \
          acc[m + (MO)][n + (NO)] = __builtin_amdgcn_mfma_f32_16x16x32_bf16(  \
              AF[m][ks], BG[n][ks], acc[m + (MO)][n + (NO)], 0, 0, 0);        \
      }                                                                       \
    }                                                                         \
    __builtin_amdgcn_s_setprio(0);                                            \
  } while (0)

#define BAR() __builtin_amdgcn_s_barrier()

    // ---- prologue: tile0 full + B0(1),A0(1); certify tile0; preload a0,b0
    STG_BH2(0, 0, 0); STG_BH2(0, 1, 0); STG_AH(0, 0, 0); STG_AH(0, 1, 0);
    STG_BH2(1, 0, 1); STG_AH(1, 0, 1);
    asm volatile("s_waitcnt vmcnt(4)" ::: "memory");  // tile0 resident
    BAR();
    LD_A0(0); LD_B0(0);

    // MODE: 2 = steady; 1 = j=62 (stage only A1B1(63); vmcnt(0) at p4);
    //       0 = j=63 (reads of own tile only; no sync)
    auto body = [&](int j, auto bfc, auto modec) {
        constexpr int BF   = decltype(bfc)::value;
        constexpr int MODE = decltype(modec)::value;
        constexpr int OF   = BF ^ 1;
        // ---- p1
        LD_A1(BF);
        if constexpr (MODE >= 1) { STG_AH(OF, 1, j + 1); STG_BH2(OF, 1, j + 1); }
        MFMA_Q(a0_, b0_, 0, 0);                       // Q1
        if constexpr (MODE >= 1) BAR();
        // ---- p2
        LD_B1(BF);
        MFMA_Q(a1_, b0_, 4, 0);                       // Q2
        if constexpr (MODE >= 1)
            asm volatile("s_waitcnt vmcnt(4)" ::: "memory"); // A0,B0(j+1) landed
        if constexpr (MODE >= 1) BAR();
        // ---- p3
        MFMA_Q(a0_, b1_, 0, 2);                       // Q3 (last use of a0_)
        if constexpr (MODE >= 1) LD_A0(OF);           // a0_ <- A0(j+1)
        if constexpr (MODE == 2) STG_BH2(BF, 0, j + 2);
        if constexpr (MODE >= 1) BAR();
        // ---- p4
        MFMA_Q(a1_, b1_, 4, 2);                       // Q4
        if constexpr (MODE >= 1) LD_B0(OF);           // b0_ <- B0(j+1)
        if constexpr (MODE == 2) {
            STG_AH(BF, 0, j + 2);
            asm volatile("s_waitcnt vmcnt(4)" ::: "memory"); // A1,B1(j+1) landed
        } else if constexpr (MODE == 1) {
            asm volatile("s_waitcnt vmcnt(0)" ::: "memory");
        }
        if constexpr (MODE >= 1) BAR();
    };

    for (int j = 0; j < 62; j += 2) {
        body(j,     IC<0>{}, IC<2>{});
        body(j + 1, IC<1>{}, IC<2>{});
    }
    body(62, IC<0>{}, IC<1>{});
    body(63, IC<1>{}, IC<0>{});

    // ---- epilogue: C/D layout col = lane&15, row = (lane>>4)*4 + i
    int q = lane >> 4;
#pragma unroll
    for (int n = 0; n < 4; ++n) {
        int col = n0 + wn * 64 + n * 16 + rl;
        float bv = bias[col];
#pragma unroll
        for (int m = 0; m < 8; ++m) {
#pragma unroll
            for (int i = 0; i < 4; ++i) {
                int row = m0 + wm * 128 + m * 16 + q * 4 + i;
                out[(size_t)row * OUT_DIM + col] = acc[m][n][i] + bv;
            }
        }
    }
#undef STG_AH
#undef STG_BH2
#undef RD_A
#undef RD_B
#undef LD_A0
#undef LD_A1
#undef LD_B0
#undef LD_B1
#undef MFMA_Q
#undef BAR
}

// ---------------------------------------------------------------- launch
extern "C" void kernel_launch(void* const* d_in, const int* in_sizes, int n_in,
                              void* d_out, int out_size, void* d_ws, size_t ws_size,
                              hipStream_t stream) {
    const float* x     = (const float*)d_in[0];
    const int*   pw    = (const int*)d_in[1];
    const float* norms = (const float*)d_in[2];
    const float* s1    = (const float*)d_in[3];
    const float* s2    = (const float*)d_in[4];
    const float* cent  = (const float*)d_in[5];
    const float* bias  = (const float*)d_in[6];
    float* out = (float*)d_out;

    size_t needX = (size_t)MROWS * IN_DIM * 2;    // 128 MB
    size_t needW = (size_t)OUT_DIM * IN_DIM * 2;  //  32 MB
    if (ws_size < needX + needW) return;

    unsigned short* Xb = (unsigned short*)d_ws;
    unsigned short* Wb = (unsigned short*)((char*)d_ws + needX);

    convert_x<<<2048, 256, 0, stream>>>(x, Xb, MROWS * IN_DIM / 8);
    decode_w<<<(OUT_DIM * 32) / 4, 256, 0, stream>>>(pw, norms, s1, s2, cent, Wb);
    gemm_bf16<<<(MROWS / 256) * (OUT_DIM / 256), 512, 0, stream>>>(Xb, Wb, bias, out);
}